// Round 3
// baseline (166.275 us; speedup 1.0000x reference)
//
#include <hip/hip_runtime.h>
#include <stdint.h>

typedef __attribute__((ext_vector_type(8))) short  bf16x8;
typedef __attribute__((ext_vector_type(4))) short  short4v;
typedef __attribute__((ext_vector_type(4))) float  f32x4;
typedef __attribute__((ext_vector_type(4))) float  float4v;

__device__ __forceinline__ unsigned short f2bf(float f) {
  unsigned int u = __builtin_bit_cast(unsigned int, f);
  u += 0x7FFFu + ((u >> 16) & 1u);          // round-to-nearest-even
  return (unsigned short)(u >> 16);
}

__device__ __forceinline__ void async_ld16(const void* g, void* l) {
  __builtin_amdgcn_global_load_lds(
      (const __attribute__((address_space(1))) void*)g,
      (__attribute__((address_space(3))) void*)l,
      16, 0, 0);
}

// ----------------------------------------------------------- fused prep ----
// blocks [0,8192): cast x->bf16 ; [8192,11264): Wqkv^T ; [11264,12288): Wproj^T
__global__ __launch_bounds__(256) void prep(
    const float* __restrict__ x, const float* __restrict__ Wqkv,
    const float* __restrict__ Wproj,
    unsigned short* __restrict__ xb, unsigned short* __restrict__ wqkvT,
    unsigned short* __restrict__ wprojT) {
  __shared__ float tile[32][33];
  const int b = blockIdx.x, tid = threadIdx.x;
  if (b < 8192) {
    int i = b * 256 + tid;
    float4v v = *(const float4v*)(x + (size_t)i * 4);
    short4v o;
    o[0] = (short)f2bf(v[0]); o[1] = (short)f2bf(v[1]);
    o[2] = (short)f2bf(v[2]); o[3] = (short)f2bf(v[3]);
    *(short4v*)(xb + (size_t)i * 4) = o;
    return;
  }
  const float* in; unsigned short* out; int R, C, bx, by;
  if (b < 11264) { int t = b - 8192;  in = Wqkv;  out = wqkvT;  R = 1024; C = 3072; bx = t % 96; by = t / 96; }
  else           { int t = b - 11264; in = Wproj; out = wprojT; R = 1024; C = 1024; bx = t & 31; by = t >> 5; }
  const int tx = tid & 31, ty = tid >> 5;
  const int c0 = bx * 32, r0 = by * 32;
  #pragma unroll
  for (int rr = ty; rr < 32; rr += 8)
    tile[rr][tx] = in[(size_t)(r0 + rr) * C + c0 + tx];
  __syncthreads();
  #pragma unroll
  for (int cc = ty; cc < 32; cc += 8)
    out[(size_t)(c0 + cc) * R + r0 + tx] = f2bf(tile[tx][cc]);
}

// ----------------------------------------------- 8-phase-style GEMM ----
// C[M,N] = A[M,K]*BT[N,K]^T. 256x256 tile, BK=32, 4 LDS sets (128KB),
// 8 waves (2Mx4N, 128x64/wave). Counted vmcnt(8), depth-3 prefetch.
template<int BF16_OUT>
__global__ __launch_bounds__(512, 1) void gemm8p(
    const unsigned short* __restrict__ A,
    const unsigned short* __restrict__ BT,
    void* __restrict__ Cout, const float* __restrict__ bias,
    int M, int N, int K) {
  constexpr int BK = 32;
  __shared__ __align__(16) unsigned short lsA[4 * 256 * BK];   // 64 KB
  __shared__ __align__(16) unsigned short lsB[4 * 256 * BK];   // 64 KB
  const int tid = threadIdx.x;
  const int ln = tid & 63, w = tid >> 6;
  const int lr = ln & 15, lq = ln >> 4;
  const int wm = w >> 2, wn = w & 3;           // 2M x 4N

  // XCD swizzle (both grids are multiples of 8)
  const int nwgx = gridDim.x;
  int wid = blockIdx.y * nwgx + blockIdx.x;
  const int nwg = nwgx * gridDim.y;
  { const int q = nwg >> 3; wid = (wid & 7) * q + (wid >> 3); }
  const int bm = (wid / nwgx) * 256, bn = (wid % nwgx) * 256;

  // ---- staging (linear LDS dest; source k-chunk pre-swizzled) ----
  const int srow = tid >> 2;                    // 0..127
  const int kc   = (tid & 3) ^ ((tid >> 3) & 3);
  const unsigned short* gA = A  + (size_t)(bm + srow) * K + kc * 8;
  const unsigned short* gB = BT + (size_t)(bn + srow) * K + kc * 8;
  const size_t rstep = (size_t)128 * K;
  char* lA = (char*)lsA + tid * 16;
  char* lB = (char*)lsB + tid * 16;

#define STG_A(c) do { const int s_ = ((c) & 3) * 16384;                     \
    async_ld16(gA + (size_t)(c) * BK,         lA + s_);                     \
    async_ld16(gA + (size_t)(c) * BK + rstep, lA + s_ + 8192); } while (0)
#define STG_B(c) do { const int s_ = ((c) & 3) * 16384;                     \
    async_ld16(gB + (size_t)(c) * BK,         lB + s_);                     \
    async_ld16(gB + (size_t)(c) * BK + rstep, lB + s_ + 8192); } while (0)

  // ---- fragment read addresses (swizzled slot = lq ^ (row>>1)&3) ----
  const int asl = (lq ^ ((lr >> 1) & 3)) << 4;
  const char* rA = (const char*)lsA + (wm * 128 + lr) * 64 + asl;
  const char* rB = (const char*)lsB + (wn * 64  + lr) * 64 + asl;

  f32x4 acc[8][4] = {};

  // prologue: stage tiles 0,1,2 (12 loads/thread-group); wait tile 0
  STG_A(0); STG_B(0); STG_A(1); STG_B(1); STG_A(2); STG_B(2);
  asm volatile("s_waitcnt vmcnt(8)" ::: "memory");
  __builtin_amdgcn_sched_barrier(0);
  __builtin_amdgcn_s_barrier();

  const int NT = K / BK;                        // 32
  for (int c = 0; c < NT; ++c) {
    const int so = (c & 3) * 16384;
    const char* pA = rA + so;
    const char* pB = rB + so;
    bf16x8 aa[4], bb[4];
    // ---- phase 0: reads, stage, barrier, wait, 16 MFMA ----
    #pragma unroll
    for (int i = 0; i < 4; ++i) bb[i] = *(const bf16x8*)(pB + i * 1024);
    #pragma unroll
    for (int i = 0; i < 4; ++i) aa[i] = *(const bf16x8*)(pA + i * 1024);
    if (c + 3 < NT) STG_A(c + 3);
    __builtin_amdgcn_s_barrier();
    asm volatile("s_waitcnt lgkmcnt(0)" ::: "memory");
    __builtin_amdgcn_sched_barrier(0);
    __builtin_amdgcn_s_setprio(1);
    #pragma unroll
    for (int mf = 0; mf < 4; ++mf)
      #pragma unroll
      for (int nf = 0; nf < 4; ++nf)
        acc[mf][nf] = __builtin_amdgcn_mfma_f32_16x16x32_bf16(aa[mf], bb[nf], acc[mf][nf], 0, 0, 0);
    __builtin_amdgcn_s_setprio(0);
    __builtin_amdgcn_s_barrier();
    // ---- phase 1 ----
    #pragma unroll
    for (int i = 0; i < 4; ++i) aa[i] = *(const bf16x8*)(pA + 4096 + i * 1024);
    if (c + 3 < NT) STG_B(c + 3);
    __builtin_amdgcn_s_barrier();
    asm volatile("s_waitcnt lgkmcnt(0)" ::: "memory");
    __builtin_amdgcn_sched_barrier(0);
    __builtin_amdgcn_s_setprio(1);
    #pragma unroll
    for (int mf = 0; mf < 4; ++mf)
      #pragma unroll
      for (int nf = 0; nf < 4; ++nf)
        acc[4 + mf][nf] = __builtin_amdgcn_mfma_f32_16x16x32_bf16(aa[mf], bb[nf], acc[4 + mf][nf], 0, 0, 0);
    __builtin_amdgcn_s_setprio(0);
    // ---- tile-end: counted wait for next tile's loads, then barrier ----
    if (c < NT - 3)       asm volatile("s_waitcnt vmcnt(8)" ::: "memory");
    else if (c == NT - 3) asm volatile("s_waitcnt vmcnt(4)" ::: "memory");
    else if (c == NT - 2) asm volatile("s_waitcnt vmcnt(0)" ::: "memory");
    __builtin_amdgcn_sched_barrier(0);
    __builtin_amdgcn_s_barrier();
  }
#undef STG_A
#undef STG_B

  // ---- epilogue ----
  if (BF16_OUT) {
    unsigned short* C = (unsigned short*)Cout;
    #pragma unroll
    for (int mf = 0; mf < 8; ++mf)
      #pragma unroll
      for (int i = 0; i < 4; ++i) {
        size_t r = (size_t)(bm + wm * 128 + mf * 16 + lq * 4 + i);
        #pragma unroll
        for (int nf = 0; nf < 4; ++nf)
          C[r * N + bn + wn * 64 + nf * 16 + lr] = f2bf(acc[mf][nf][i]);
      }
  } else {
    float* C = (float*)Cout;
    float bv[4];
    #pragma unroll
    for (int nf = 0; nf < 4; ++nf)
      bv[nf] = bias ? bias[bn + wn * 64 + nf * 16 + lr] : 0.f;
    #pragma unroll
    for (int mf = 0; mf < 8; ++mf)
      #pragma unroll
      for (int i = 0; i < 4; ++i) {
        size_t r = (size_t)(bm + wm * 128 + mf * 16 + lq * 4 + i);
        #pragma unroll
        for (int nf = 0; nf < 4; ++nf)
          C[r * N + bn + wn * 64 + nf * 16 + lr] = acc[mf][nf][i] + bv[nf];
      }
  }
}

// --------------------------------- partial M^T = scale*(k^T v)^T over j ----
// block = unit*4 + p ; unit = b*32 + h*2 + half ; p = j-quarter (256 rows)
__global__ __launch_bounds__(256) void kv_outer(
    const unsigned short* __restrict__ qkv,
    unsigned short* __restrict__ MT, float scale) {
  const int bid = blockIdx.x;
  const int p = bid & 3, unit = bid >> 2;
  const int b = unit >> 5, h = (unit >> 1) & 15, hf = unit & 1;
  const size_t base = ((size_t)(b * 2048 + hf * 1024)) * 3072 + h * 64;
  const unsigned short* kp = qkv + base + 1024;
  const unsigned short* vp = qkv + base + 2048;
  __shared__ __align__(16) unsigned short kT[64][136];
  __shared__ __align__(16) unsigned short vT[64][136];
  const int tid = threadIdx.x, wv = tid >> 6, ln = tid & 63;
  f32x4 acc[4] = {};
  const int e4 = (tid & 15) * 4;
  const int jr = tid >> 4;
  const int fr = ln & 15, ko = (ln >> 4) * 8;

  for (int j0 = p * 256; j0 < p * 256 + 256; j0 += 128) {
    __syncthreads();
    #pragma unroll
    for (int jj = 0; jj < 128; jj += 16) {
      int j = jj + jr;
      size_t go = (size_t)(j0 + j) * 3072 + e4;
      short4v k4 = *(const short4v*)(kp + go);
      short4v v4 = *(const short4v*)(vp + go);
      #pragma unroll
      for (int t = 0; t < 4; t++) {
        kT[e4 + t][j] = (unsigned short)k4[t];
        vT[e4 + t][j] = (unsigned short)v4[t];
      }
    }
    __syncthreads();
    #pragma unroll
    for (int kk = 0; kk < 128; kk += 32) {
      bf16x8 af = *(const bf16x8*)&kT[wv * 16 + fr][kk + ko];
      #pragma unroll
      for (int n = 0; n < 4; n++) {
        bf16x8 bf2 = *(const bf16x8*)&vT[n * 16 + fr][kk + ko];
        acc[n] = __builtin_amdgcn_mfma_f32_16x16x32_bf16(af, bf2, acc[n], 0, 0, 0);
      }
    }
  }
  unsigned short* outp = MT + (size_t)bid * 4096;       // [d][e], 64x64
  #pragma unroll
  for (int n = 0; n < 4; n++)
    #pragma unroll
    for (int i = 0; i < 4; i++) {
      int d = n * 16 + fr;
      int e = wv * 16 + (ln >> 4) * 4 + i;
      outp[d * 64 + e] = f2bf(acc[n][i] * scale);
    }
}

// ---------------------------------------------- o = q * sum_p M_p ----------
__global__ __launch_bounds__(256) void apply_q(
    const unsigned short* __restrict__ qkv,
    const unsigned short* __restrict__ MT,
    unsigned short* __restrict__ o) {
  const int bid = blockIdx.x;     // ((b*16+h)*2 + lhalf)*16 + lt
  const int lt = bid & 15, hf = (bid >> 4) & 1, h = (bid >> 5) & 15, b = bid >> 9;
  const int l0 = hf * 1024 + lt * 64;
  const unsigned short* qp = qkv + ((size_t)(b * 2048 + l0)) * 3072 + h * 64;
  const int unit_other = (b * 16 + h) * 2 + (1 - hf);
  const unsigned short* mp = MT + (size_t)unit_other * 4 * 4096;
  const int tid = threadIdx.x, wv = tid >> 6, ln = tid & 63;
  const int fr = ln & 15, ko = (ln >> 4) * 8;
  f32x4 acc[4] = {};
  bf16x8 af[2];
  #pragma unroll
  for (int kk = 0; kk < 2; kk++)
    af[kk] = *(const bf16x8*)(qp + (size_t)(wv * 16 + fr) * 3072 + kk * 32 + ko);
  #pragma unroll
  for (int p = 0; p < 4; ++p)
    #pragma unroll
    for (int kk = 0; kk < 2; kk++)
      #pragma unroll
      for (int n = 0; n < 4; n++) {
        bf16x8 bf2 = *(const bf16x8*)(mp + p * 4096 + (n * 16 + fr) * 64 + kk * 32 + ko);
        acc[n] = __builtin_amdgcn_mfma_f32_16x16x32_bf16(af[kk], bf2, acc[n], 0, 0, 0);
      }
  unsigned short* op = o + ((size_t)(b * 2048 + l0)) * 1024 + h * 64;
  #pragma unroll
  for (int n = 0; n < 4; n++)
    #pragma unroll
    for (int i = 0; i < 4; i++)
      op[(size_t)(wv * 16 + (ln >> 4) * 4 + i) * 1024 + n * 16 + fr] = f2bf(acc[n][i]);
}

// ---------------------------------------------------------------------------
extern "C" void kernel_launch(void* const* d_in, const int* in_sizes, int n_in,
                              void* d_out, int out_size, void* d_ws, size_t ws_size,
                              hipStream_t stream) {
  const float* x     = (const float*)d_in[0];   // 4 x 2048 x 1024
  const float* Wqkv  = (const float*)d_in[1];   // 1024 x 3072
  const float* Wproj = (const float*)d_in[2];   // 1024 x 1024
  const float* bproj = (const float*)d_in[3];   // 1024
  float* out = (float*)d_out;                   // 8192 x 1024

  char* ws = (char*)d_ws;
  unsigned short* xb     = (unsigned short*)(ws);               // 16.78 MB
  unsigned short* MT     = (unsigned short*)(ws);               // 4 MB, aliases xb (xb dead after GEMM1)
  unsigned short* wqkvT  = (unsigned short*)(ws + 16777216);    //  6.29 MB
  unsigned short* wprojT = (unsigned short*)(ws + 23068672);    //  2.10 MB
  unsigned short* qkv    = (unsigned short*)(ws + 25165824);    // 50.33 MB
  unsigned short* ob     = (unsigned short*)(ws + 75497472);    // 16.78 MB

  // fused cast + weight transposes
  prep<<<12288, 256, 0, stream>>>(x, Wqkv, Wproj, xb, wqkvT, wprojT);

  // qkv = x @ W_qkv   (8192 x 3072, bf16 out) — 384 blocks (%8==0)
  gemm8p<1><<<dim3(12, 32), 512, 0, stream>>>(xb, wqkvT, (void*)qkv, nullptr,
                                              8192, 3072, 1024);
  // partial M^T per (b,h,half, j-quarter) — 512 blocks
  kv_outer<<<512, 256, 0, stream>>>(qkv, MT, 0.125f);
  // o = q @ sum_p M_p(other half)
  apply_q<<<2048, 256, 0, stream>>>(qkv, MT, ob);
  // out = o @ W_proj + b  (fp32 out) — 128 blocks (%8==0)
  gemm8p<0><<<dim3(4, 32), 512, 0, stream>>>(ob, wprojT, (void*)out, bproj,
                                             8192, 1024, 1024);
}